// Round 9
// baseline (371.393 us; speedup 1.0000x reference)
//
#include <hip/hip_runtime.h>
#include <hip/hip_bf16.h>

#define D_DIM 512
#define H_DIM 512
#define G_SEG 1024
#define BM    64

typedef __attribute__((ext_vector_type(8))) short bf16x8;
typedef __attribute__((ext_vector_type(4))) float f32x4;
typedef unsigned int u32;
typedef unsigned short u16;

// ---- workspace ----
#define WS_S    0                      // G f32
#define WS_BETA 8192                   // N f32 (1 MB)
#define WS_WB   (8192 + (1u << 20))    // 512 KB bf16 W granule layout

// ---- LDS (gemm_beta) ----
#define AS_BYTES  (BM * 1024)          // 64 rows x 1024B bf16, XOR-swizzled
#define BETA_OFF  AS_BYTES             // 4 col-groups x 64 f32
#define LDS_K1    (BETA_OFF + 4 * BM * 4)

static __device__ __forceinline__ u16 f2bf(float f) {
    __hip_bfloat16 h = __float2bfloat16(f);
    return *(u16*)&h;
}
static __device__ __forceinline__ float fast_tanh(float x) {
    float e = exp2f(x * 2.885390081777927f);   // e^(2x)
    return 1.0f - 2.0f * __builtin_amdgcn_rcpf(e + 1.0f);
}
static __device__ __forceinline__ void pack8(const float4& a, const float4& b, void* dst) {
    u16 h[8];
    h[0]=f2bf(a.x); h[1]=f2bf(a.y); h[2]=f2bf(a.z); h[3]=f2bf(a.w);
    h[4]=f2bf(b.x); h[5]=f2bf(b.y); h[6]=f2bf(b.z); h[7]=f2bf(b.w);
    *(uint4*)dst = *(uint4*)h;
}

// ---- W fp32 -> bf16 granule layout: byte ((k32*512 + c)*4 + lhi)*16 = W[c][k32*32+lhi*8 ..+8]
__global__ __launch_bounds__(256)
void cvt_w(const float* __restrict__ W, u16* __restrict__ Wb) {
    int t   = blockIdx.x * 256 + threadIdx.x;   // 32768 granules
    int lhi = t & 3;
    int c   = (t >> 2) & 511;
    int k32 = t >> 11;
    const float* src = W + (size_t)c * 512 + k32 * 32 + lhi * 8;
    float4 f0 = *(const float4*)(src);
    float4 f1 = *(const float4*)(src + 4);
    pack8(f0, f1, Wb + (size_t)t * 8);
}

// ---- K1: GEMM(64 x 512 x 512) + tanh*V reduce -> beta[n] (pure, no atomics) ----
// 4 waves x (64 rows x 128 cols): acc[4][8]; b double-buffered from L2-resident Wb.
__global__ __launch_bounds__(256, 2)
void gemm_beta(const float* __restrict__ E, const u16* __restrict__ Wb,
               const float* __restrict__ V, float* __restrict__ betaOut)
{
    extern __shared__ char smem[];
    const int tid = threadIdx.x;
    const int nodeBase = blockIdx.x * BM;
    const int l   = tid & 63;
    const int w   = tid >> 6;     // col group: cols [w*128, w*128+128)
    const int l15 = l & 15;
    const int lhi = l >> 4;

    const float* Eb = E + (size_t)nodeBase * 512;

    // ---- stage the FULL 64x512 A-tile (fp32 -> bf16, swizzled), 4 batches ----
#pragma unroll 1
    for (int p = 0; p < 4; ++p) {
        float4 L[8];
        const int ci0 = p * 1024 + tid * 4;     // ushort8-chunk index
#pragma unroll
        for (int j = 0; j < 4; ++j) {
            int ci = ci0 + j;
            int row = ci >> 6, cc = ci & 63;
            const float* src = Eb + (size_t)row * 512 + cc * 8;
            L[2*j]   = *(const float4*)src;
            L[2*j+1] = *(const float4*)(src + 4);
        }
#pragma unroll
        for (int j = 0; j < 4; ++j) {
            int ci = ci0 + j;
            int row = ci >> 6, cc = ci & 63;
            int byte0 = row * 1024 + ((cc * 16) ^ ((row & 7) << 4));
            pack8(L[2*j], L[2*j+1], smem + byte0);
        }
    }
    __syncthreads();

    // ---- K-loop: 16 steps of 32k, b double-buffered in registers ----
    f32x4 acc[4][8];
#pragma unroll
    for (int m = 0; m < 4; ++m)
#pragma unroll
        for (int n = 0; n < 8; ++n) acc[m][n] = (f32x4){0.f, 0.f, 0.f, 0.f};

    const int bOffBase = ((w * 128 + l15) * 4 + lhi) * 16;   // + n*1024
    const char* Wbb = (const char*)Wb;

    bf16x8 bA[8], bB[8];
#pragma unroll
    for (int n = 0; n < 8; ++n)
        bA[n] = *(const bf16x8*)(Wbb + bOffBase + n * 1024);

#pragma unroll 1
    for (int kk2 = 0; kk2 < 8; ++kk2) {
        {   // half A: compute kk=2*kk2 with bA; prefetch bB for kk+1
            const char* Wn = Wbb + ((size_t)(2 * kk2 + 1) << 15);
#pragma unroll
            for (int n = 0; n < 8; ++n)
                bB[n] = *(const bf16x8*)(Wn + bOffBase + n * 1024);
            bf16x8 a[4];
            const int kbyte = (2 * kk2) * 64 + lhi * 16;
#pragma unroll
            for (int m = 0; m < 4; ++m) {
                int row = m * 16 + l15;
                a[m] = *(const bf16x8*)(smem + row * 1024 + (kbyte ^ ((row & 7) << 4)));
            }
#pragma unroll
            for (int m = 0; m < 4; ++m)
#pragma unroll
                for (int n = 0; n < 8; ++n)
                    acc[m][n] = __builtin_amdgcn_mfma_f32_16x16x32_bf16(a[m], bA[n], acc[m][n], 0, 0, 0);
        }
        {   // half B: compute kk=2*kk2+1 with bB; prefetch bA for next kk2
            if (kk2 < 7) {
                const char* Wn = Wbb + ((size_t)(2 * kk2 + 2) << 15);
#pragma unroll
                for (int n = 0; n < 8; ++n)
                    bA[n] = *(const bf16x8*)(Wn + bOffBase + n * 1024);
            }
            bf16x8 a[4];
            const int kbyte = (2 * kk2 + 1) * 64 + lhi * 16;
#pragma unroll
            for (int m = 0; m < 4; ++m) {
                int row = m * 16 + l15;
                a[m] = *(const bf16x8*)(smem + row * 1024 + (kbyte ^ ((row & 7) << 4)));
            }
#pragma unroll
            for (int m = 0; m < 4; ++m)
#pragma unroll
                for (int n = 0; n < 8; ++n)
                    acc[m][n] = __builtin_amdgcn_mfma_f32_16x16x32_bf16(a[m], bB[n], acc[m][n], 0, 0, 0);
        }
    }

    // ---- epilogue: beta-partial[row] over this wave's 128 cols ----
    float Vv[8];
#pragma unroll
    for (int n = 0; n < 8; ++n)
        Vv[n] = V[w * 128 + n * 16 + l15];

    float bsum[4][4];
#pragma unroll
    for (int m = 0; m < 4; ++m)
#pragma unroll
        for (int r = 0; r < 4; ++r) {
            float s = 0.f;
#pragma unroll
            for (int n = 0; n < 8; ++n)
                s += Vv[n] * fast_tanh(acc[m][n][r]);
            bsum[m][r] = s;
        }
#pragma unroll
    for (int off = 1; off <= 8; off <<= 1)
#pragma unroll
        for (int m = 0; m < 4; ++m)
#pragma unroll
            for (int r = 0; r < 4; ++r)
                bsum[m][r] += __shfl_xor(bsum[m][r], off, 64);

    float* betaP = (float*)(smem + BETA_OFF);   // [4 col-groups][64 rows]
    if (l15 == 0) {
#pragma unroll
        for (int m = 0; m < 4; ++m)
#pragma unroll
            for (int r = 0; r < 4; ++r)
                betaP[w * BM + m * 16 + lhi * 4 + r] = bsum[m][r];
    }
    __syncthreads();

    if (tid < BM) {
        float beta = betaP[tid] + betaP[BM + tid] + betaP[2 * BM + tid] + betaP[3 * BM + tid];
        betaOut[nodeBase + tid] = beta;
    }
}

// ---- K2: eb = exp(beta); S[g] += eb; out_raw[g][c] += eb * E[n][c] ----
// 256 rows/block; lane-contiguous atomics (round-4 lesson); fp32 E streamed.
__global__ __launch_bounds__(256)
void wsum_eb(const float* __restrict__ E, const int* __restrict__ BI,
             const float* __restrict__ beta, float* __restrict__ S,
             float* __restrict__ out)
{
    __shared__ float al[256];
    __shared__ int   sg[256];
    const int t = threadIdx.x;
    const int base = blockIdx.x * 256;
    {
        int n = base + t;
        float eb = expf(beta[n]);
        al[t] = eb;
        int g = BI[n];
        sg[t] = g;
        int g0 = __shfl(g, 0, 64);
        if (__all(g == g0)) {
            float s = eb;
#pragma unroll
            for (int off = 1; off <= 32; off <<= 1)
                s += __shfl_xor(s, off, 64);
            if ((t & 63) == 0) atomicAdd(&S[g], s);
        } else {
            atomicAdd(&S[g], eb);
        }
    }
    __syncthreads();

    const int c4 = (t & 127) * 4;     // threads 0..127 tile the 512 cols in float4s
    const int rg = t >> 7;            // 2 row groups, interleaved stride 2
    float a0 = 0.f, a1 = 0.f, a2 = 0.f, a3 = 0.f;
    int gcur = sg[rg];
#pragma unroll 1
    for (int r = rg; r < 256; r += 2) {
        int g = sg[r];
        if (g != gcur) {
            float* o = out + (size_t)gcur * 512 + c4;
            atomicAdd(o, a0); atomicAdd(o + 1, a1); atomicAdd(o + 2, a2); atomicAdd(o + 3, a3);
            a0 = a1 = a2 = a3 = 0.f; gcur = g;
        }
        float wgt = al[r];
        float4 v = *(const float4*)(E + (size_t)(base + r) * 512 + c4);
        a0 += wgt * v.x; a1 += wgt * v.y; a2 += wgt * v.z; a3 += wgt * v.w;
    }
    float* o = out + (size_t)gcur * 512 + c4;
    atomicAdd(o, a0); atomicAdd(o + 1, a1); atomicAdd(o + 2, a2); atomicAdd(o + 3, a3);
}

__global__ __launch_bounds__(256)
void finalize_kernel(float* __restrict__ out, const float* __restrict__ S) {
    int idx = blockIdx.x * 256 + threadIdx.x;
    float s = S[idx >> 9];
    float v = out[idx];
    out[idx] = (s != 0.f) ? v * __builtin_amdgcn_rcpf(s) : 0.f;
}

extern "C" void kernel_launch(void* const* d_in, const int* in_sizes, int n_in,
                              void* d_out, int out_size, void* d_ws, size_t ws_size,
                              hipStream_t stream) {
    const float* E  = (const float*)d_in[0];
    const int*   BI = (const int*)d_in[1];
    const float* W  = (const float*)d_in[2];
    const float* V  = (const float*)d_in[3];
    float* out = (float*)d_out;
    char*  ws  = (char*)d_ws;
    const int Ntot = in_sizes[0] / D_DIM;

    float* S    = (float*)(ws + WS_S);
    float* beta = (float*)(ws + WS_BETA);
    u16*   Wb   = (u16*)(ws + WS_WB);

    hipMemsetAsync(S, 0, G_SEG * 4, stream);
    hipMemsetAsync(out, 0, (size_t)out_size * 4, stream);
    hipFuncSetAttribute((const void*)gemm_beta,
                        hipFuncAttributeMaxDynamicSharedMemorySize, LDS_K1);

    cvt_w<<<128, 256, 0, stream>>>(W, Wb);
    gemm_beta<<<Ntot / BM, 256, LDS_K1, stream>>>(E, Wb, V, beta);
    wsum_eb<<<Ntot / 256, 256, 0, stream>>>(E, BI, beta, S, out);
    finalize_kernel<<<out_size / 256, 256, 0, stream>>>(out, S);
}

// Round 10
// 351.860 us; speedup vs baseline: 1.0555x; 1.0555x over previous
//
#include <hip/hip_runtime.h>
#include <hip/hip_bf16.h>

#define D_DIM 512
#define H_DIM 512
#define G_SEG 1024
#define BM    64

typedef __attribute__((ext_vector_type(8))) short bf16x8;
typedef __attribute__((ext_vector_type(4))) float f32x4;
typedef unsigned int u32;
typedef unsigned short u16;

// ---- workspace ----
#define WS_S   0         // G f32
#define WS_WB  8192      // 512 KB bf16 W in MFMA-fragment granule layout

// ---- LDS layout ----
#define AS_BYTES  (BM * 1024)                 // 64 rows x 1024B bf16, XOR-swizzled
#define BETA_OFF  AS_BYTES                    // 4 col-groups x 64 f32
#define EBS_OFF   (BETA_OFF + 4 * BM * 4)
#define SIDX_OFF  (EBS_OFF + BM * 4)
#define SCR_OFF   (SIDX_OFF + BM * 4)         // 4 waves x 512 f32 flush scratch
#define LDS_TOTAL (SCR_OFF + 4 * 512 * 4)

static __device__ __forceinline__ u16 f2bf(float f) {
    __hip_bfloat16 h = __float2bfloat16(f);
    return *(u16*)&h;
}
static __device__ __forceinline__ float bf2f(u16 u) {
    return __uint_as_float(((u32)u) << 16);
}
static __device__ __forceinline__ float fast_tanh(float x) {
    float e = exp2f(x * 2.885390081777927f);   // e^(2x)
    return 1.0f - 2.0f * __builtin_amdgcn_rcpf(e + 1.0f);
}
static __device__ __forceinline__ void pack8(const float4& a, const float4& b, void* dst) {
    u16 h[8];
    h[0]=f2bf(a.x); h[1]=f2bf(a.y); h[2]=f2bf(a.z); h[3]=f2bf(a.w);
    h[4]=f2bf(b.x); h[5]=f2bf(b.y); h[6]=f2bf(b.z); h[7]=f2bf(b.w);
    *(uint4*)dst = *(uint4*)h;
}

// ---- W fp32 -> bf16 granule layout: byte ((k32*512 + c)*4 + lhi)*16 = W[c][k32*32+lhi*8 ..+8]
__global__ __launch_bounds__(256)
void cvt_w(const float* __restrict__ W, u16* __restrict__ Wb) {
    int t   = blockIdx.x * 256 + threadIdx.x;   // 32768 granules
    int lhi = t & 3;
    int c   = (t >> 2) & 511;
    int k32 = t >> 11;
    const float* src = W + (size_t)c * 512 + k32 * 32 + lhi * 8;
    float4 f0 = *(const float4*)(src);
    float4 f1 = *(const float4*)(src + 4);
    pack8(f0, f1, Wb + (size_t)t * 8);
}

// ---- fused: GEMM(64 x 512 x 512) + tanh*V reduce + exp + segment sums ----
// 4 waves x (64 rows x 128 cols): acc[4][8]; barrier-free K-loop, b reg-dbuf.
// Staging: every global load instruction covers 1KB CONTIGUOUS (one row-half,
// lane l -> bytes l*16), software-pipelined LA/LB rounds.
__global__ __launch_bounds__(256, 2)
void fused(const float* __restrict__ E, const int* __restrict__ BI,
           const u16* __restrict__ Wb, const float* __restrict__ V,
           float* __restrict__ out, float* __restrict__ S)
{
    extern __shared__ char smem[];
    const int tid = threadIdx.x;
    const int nodeBase = blockIdx.x * BM;
    const int l   = tid & 63;
    const int w   = tid >> 6;     // col group: cols [w*128, w*128+128)
    const int l15 = l & 15;
    const int lhi = l >> 4;

    const float* Eb = E + (size_t)nodeBase * 512;

    // ---- coalesced, pipelined staging of the 64x512 A-tile (fp32 -> bf16, swizzled)
    {
        const int rbase0 = w * 16;
        float4 LA[8], LB[8];
        auto loadRound = [&](int p, float4* L) {
#pragma unroll
            for (int i = 0; i < 8; ++i) {
                int row  = rbase0 + p * 4 + (i >> 1);
                int half = i & 1;
                L[i] = *(const float4*)(Eb + (size_t)row * 512 + half * 256 + l * 4);
            }
        };
        auto writeRound = [&](int p, float4* L) {
#pragma unroll
            for (int i = 0; i < 8; ++i) {
                int row  = rbase0 + p * 4 + (i >> 1);
                int half = i & 1;
                int g16  = half * 32 + (l >> 1);
                int byte = row * 1024 + ((g16 * 16) ^ ((row & 7) << 4)) + (l & 1) * 8;
                u16 h[4];
                h[0] = f2bf(L[i].x); h[1] = f2bf(L[i].y);
                h[2] = f2bf(L[i].z); h[3] = f2bf(L[i].w);
                *(uint2*)(smem + byte) = *(uint2*)h;
            }
        };
        loadRound(0, LA);
        loadRound(1, LB);
        writeRound(0, LA);
        loadRound(2, LA);
        writeRound(1, LB);
        loadRound(3, LB);
        writeRound(2, LA);
        writeRound(3, LB);
    }
    __syncthreads();

    // ---- K-loop: 16 steps of 32k, b double-buffered in registers ----
    f32x4 acc[4][8];
#pragma unroll
    for (int m = 0; m < 4; ++m)
#pragma unroll
        for (int n = 0; n < 8; ++n) acc[m][n] = (f32x4){0.f, 0.f, 0.f, 0.f};

    const int bOffBase = ((w * 128 + l15) * 4 + lhi) * 16;   // + n*1024
    const char* Wbb = (const char*)Wb;

    bf16x8 bA[8], bB[8];
#pragma unroll
    for (int n = 0; n < 8; ++n)
        bA[n] = *(const bf16x8*)(Wbb + bOffBase + n * 1024);

#pragma unroll 1
    for (int kk2 = 0; kk2 < 8; ++kk2) {
        {   // half A: compute kk=2*kk2 with bA; prefetch bB for kk+1
            const char* Wn = Wbb + ((size_t)(2 * kk2 + 1) << 15);
#pragma unroll
            for (int n = 0; n < 8; ++n)
                bB[n] = *(const bf16x8*)(Wn + bOffBase + n * 1024);
            bf16x8 a[4];
            const int kbyte = (2 * kk2) * 64 + lhi * 16;
#pragma unroll
            for (int m = 0; m < 4; ++m) {
                int row = m * 16 + l15;
                a[m] = *(const bf16x8*)(smem + row * 1024 + (kbyte ^ ((row & 7) << 4)));
            }
#pragma unroll
            for (int m = 0; m < 4; ++m)
#pragma unroll
                for (int n = 0; n < 8; ++n)
                    acc[m][n] = __builtin_amdgcn_mfma_f32_16x16x32_bf16(a[m], bA[n], acc[m][n], 0, 0, 0);
        }
        {   // half B: compute kk=2*kk2+1 with bB; prefetch bA for next kk2
            if (kk2 < 7) {
                const char* Wn = Wbb + ((size_t)(2 * kk2 + 2) << 15);
#pragma unroll
                for (int n = 0; n < 8; ++n)
                    bA[n] = *(const bf16x8*)(Wn + bOffBase + n * 1024);
            }
            bf16x8 a[4];
            const int kbyte = (2 * kk2 + 1) * 64 + lhi * 16;
#pragma unroll
            for (int m = 0; m < 4; ++m) {
                int row = m * 16 + l15;
                a[m] = *(const bf16x8*)(smem + row * 1024 + (kbyte ^ ((row & 7) << 4)));
            }
#pragma unroll
            for (int m = 0; m < 4; ++m)
#pragma unroll
                for (int n = 0; n < 8; ++n)
                    acc[m][n] = __builtin_amdgcn_mfma_f32_16x16x32_bf16(a[m], bB[n], acc[m][n], 0, 0, 0);
        }
    }

    // ---- epilogue: beta-partial[row] = sum over this wave's 128 cols of V*tanh
    float Vv[8];
#pragma unroll
    for (int n = 0; n < 8; ++n)
        Vv[n] = V[w * 128 + n * 16 + l15];

    float bsum[4][4];
#pragma unroll
    for (int m = 0; m < 4; ++m)
#pragma unroll
        for (int r = 0; r < 4; ++r) {
            float s = 0.f;
#pragma unroll
            for (int n = 0; n < 8; ++n)
                s += Vv[n] * fast_tanh(acc[m][n][r]);
            bsum[m][r] = s;
        }
#pragma unroll
    for (int off = 1; off <= 8; off <<= 1)
#pragma unroll
        for (int m = 0; m < 4; ++m)
#pragma unroll
            for (int r = 0; r < 4; ++r)
                bsum[m][r] += __shfl_xor(bsum[m][r], off, 64);

    float* betaP = (float*)(smem + BETA_OFF);   // [4 col-groups][64 rows]
    if (l15 == 0) {
#pragma unroll
        for (int m = 0; m < 4; ++m)
#pragma unroll
            for (int r = 0; r < 4; ++r)
                betaP[w * BM + m * 16 + lhi * 4 + r] = bsum[m][r];
    }
    __syncthreads();

    // ---- eb = exp(beta); S[g] += eb (wave 0; rows sorted) ----
    float* ebs  = (float*)(smem + EBS_OFF);
    int*   sidx = (int*)(smem + SIDX_OFF);
    if (tid < BM) {
        float beta = betaP[tid] + betaP[BM + tid] + betaP[2 * BM + tid] + betaP[3 * BM + tid];
        float eb = expf(beta);
        ebs[tid] = eb;
        int g = BI[nodeBase + tid];
        sidx[tid] = g;
        int g0 = __shfl(g, 0, 64);
        if (__all(g == g0)) {
            float s = eb;
#pragma unroll
            for (int off = 1; off <= 32; off <<= 1)
                s += __shfl_xor(s, off, 64);
            if (l == 0) atomicAdd(&S[g], s);
        } else {
            atomicAdd(&S[g], eb);
        }
    }
    __syncthreads();

    // ---- weighted segment sum: wave w owns rows [16w,16w+16); lane l cols [8l,8l+8).
    // Flushes transpose through per-wave LDS scratch -> lane-contiguous atomics.
    {
        float* scr = (float*)(smem + SCR_OFF) + w * 512;
        const int rbase = w * 16;
        float a8[8];
#pragma unroll
        for (int j = 0; j < 8; ++j) a8[j] = 0.f;
        int gcur = sidx[rbase];

#pragma unroll 1
        for (int rr = 0; rr < 16; ++rr) {
            int r = rbase + rr;
            int g = sidx[r];                     // wave-uniform
            if (g != gcur) {
                *(float4*)(scr + l * 8)     = make_float4(a8[0], a8[1], a8[2], a8[3]);
                *(float4*)(scr + l * 8 + 4) = make_float4(a8[4], a8[5], a8[6], a8[7]);
                asm volatile("s_waitcnt lgkmcnt(0)" ::: "memory");
#pragma unroll
                for (int j = 0; j < 8; ++j)
                    atomicAdd(&out[(size_t)gcur * 512 + j * 64 + l], scr[j * 64 + l]);
#pragma unroll
                for (int j = 0; j < 8; ++j) a8[j] = 0.f;
                gcur = g;
            }
            float wgt = ebs[r];
            bf16x8 v = *(const bf16x8*)(smem + r * 1024 + ((l * 16) ^ ((r & 7) << 4)));
#pragma unroll
            for (int j = 0; j < 8; ++j)
                a8[j] += wgt * bf2f((u16)v[j]);
        }
        *(float4*)(scr + l * 8)     = make_float4(a8[0], a8[1], a8[2], a8[3]);
        *(float4*)(scr + l * 8 + 4) = make_float4(a8[4], a8[5], a8[6], a8[7]);
        asm volatile("s_waitcnt lgkmcnt(0)" ::: "memory");
#pragma unroll
        for (int j = 0; j < 8; ++j)
            atomicAdd(&out[(size_t)gcur * 512 + j * 64 + l], scr[j * 64 + l]);
    }
}

__global__ __launch_bounds__(256)
void finalize_kernel(float* __restrict__ out, const float* __restrict__ S) {
    int idx = blockIdx.x * 256 + threadIdx.x;
    float s = S[idx >> 9];
    float v = out[idx];
    out[idx] = (s != 0.f) ? v * __builtin_amdgcn_rcpf(s) : 0.f;
}

extern "C" void kernel_launch(void* const* d_in, const int* in_sizes, int n_in,
                              void* d_out, int out_size, void* d_ws, size_t ws_size,
                              hipStream_t stream) {
    const float* E  = (const float*)d_in[0];
    const int*   BI = (const int*)d_in[1];
    const float* W  = (const float*)d_in[2];
    const float* V  = (const float*)d_in[3];
    float* out = (float*)d_out;
    char*  ws  = (char*)d_ws;
    const int Ntot = in_sizes[0] / D_DIM;

    float* S  = (float*)(ws + WS_S);
    u16*   Wb = (u16*)(ws + WS_WB);

    hipMemsetAsync(S, 0, G_SEG * 4, stream);
    hipMemsetAsync(out, 0, (size_t)out_size * 4, stream);
    hipFuncSetAttribute((const void*)fused,
                        hipFuncAttributeMaxDynamicSharedMemorySize, LDS_TOTAL);

    cvt_w<<<128, 256, 0, stream>>>(W, Wb);
    fused<<<Ntot / BM, 256, LDS_TOTAL, stream>>>(E, BI, Wb, V, out, S);
    finalize_kernel<<<out_size / 256, 256, 0, stream>>>(out, S);
}

// Round 11
// 346.870 us; speedup vs baseline: 1.0707x; 1.0144x over previous
//
#include <hip/hip_runtime.h>
#include <hip/hip_bf16.h>

#define D_DIM 512
#define H_DIM 512
#define G_SEG 1024
#define BM    64
#define TILES 8

typedef __attribute__((ext_vector_type(8))) short bf16x8;
typedef __attribute__((ext_vector_type(4))) float f32x4;
typedef unsigned int u32;
typedef unsigned short u16;

// ---- workspace ----
#define WS_S   0         // G f32
#define WS_WB  8192      // 512 KB bf16 W in MFMA-fragment granule layout

// ---- LDS layout: two 64-row A-buffers + misc ----
#define BUF0_OFF  0
#define BUF1_OFF  (BM * 1024)
#define BETA_OFF  (2 * BM * 1024)             // 4 col-groups x 64 f32
#define EBS_OFF   (BETA_OFF + 4 * BM * 4)
#define SIDX_OFF  (EBS_OFF + BM * 4)
#define SCR_OFF   (SIDX_OFF + BM * 4)         // 4 waves x 512 f32 flush scratch
#define LDS_TOTAL (SCR_OFF + 4 * 512 * 4)     // 140800 B -> 1 block/CU

static __device__ __forceinline__ u16 f2bf(float f) {
    __hip_bfloat16 h = __float2bfloat16(f);
    return *(u16*)&h;
}
static __device__ __forceinline__ float bf2f(u16 u) {
    return __uint_as_float(((u32)u) << 16);
}
static __device__ __forceinline__ float fast_tanh(float x) {
    float e = exp2f(x * 2.885390081777927f);   // e^(2x)
    return 1.0f - 2.0f * __builtin_amdgcn_rcpf(e + 1.0f);
}
// LDS-only barrier: do NOT drain vmcnt (keeps next-tile prefetch in flight).
// Cross-wave data through LDS needs lgkmcnt(0); global loads land in registers.
static __device__ __forceinline__ void barrier_lds() {
    asm volatile("s_waitcnt lgkmcnt(0)" ::: "memory");
    __builtin_amdgcn_s_barrier();
    __builtin_amdgcn_sched_barrier(0);
}

// ---- W fp32 -> bf16 granule layout: byte ((k32*512 + c)*4 + lhi)*16 = W[c][k32*32+lhi*8 ..+8]
__global__ __launch_bounds__(256)
void cvt_w(const float* __restrict__ W, u16* __restrict__ Wb) {
    int t   = blockIdx.x * 256 + threadIdx.x;   // 32768 granules
    int lhi = t & 3;
    int c   = (t >> 2) & 511;
    int k32 = t >> 11;
    const float* src = W + (size_t)c * 512 + k32 * 32 + lhi * 8;
    float4 f0 = *(const float4*)(src);
    float4 f1 = *(const float4*)(src + 4);
    u16 h[8];
    h[0]=f2bf(f0.x); h[1]=f2bf(f0.y); h[2]=f2bf(f0.z); h[3]=f2bf(f0.w);
    h[4]=f2bf(f1.x); h[5]=f2bf(f1.y); h[6]=f2bf(f1.z); h[7]=f2bf(f1.w);
    *(uint4*)(Wb + (size_t)t * 8) = *(uint4*)h;
}

// ---- persistent fused kernel: each block processes TILES consecutive 64-row tiles
// with double-buffered LDS staging overlapped against compute (loads always in flight).
__global__ __launch_bounds__(256, 1)
void fused(const float* __restrict__ E, const int* __restrict__ BI,
           const u16* __restrict__ Wb, const float* __restrict__ V,
           float* __restrict__ out, float* __restrict__ S)
{
    extern __shared__ char smem[];
    const int tid = threadIdx.x;
    const int l   = tid & 63;
    const int w   = tid >> 6;     // col group: cols [w*128, w*128+128)
    const int l15 = l & 15;
    const int lhi = l >> 4;
    const int tile0 = blockIdx.x * TILES;

    const int bOffBase = ((w * 128 + l15) * 4 + lhi) * 16;   // + n*1024
    const char* Wbb = (const char*)Wb;

    float4 LA[8], LB[8];
    // staging: batch p covers rows [w*16 + p*4, +4); each load instr = 1KB contiguous.
    auto issueB = [&](int gTile, int p, float4* L) {
        const float* Eb = E + (size_t)gTile * (BM * 512);
#pragma unroll
        for (int i = 0; i < 8; ++i) {
            int row  = w * 16 + p * 4 + (i >> 1);
            int half = i & 1;
            L[i] = *(const float4*)(Eb + (size_t)row * 512 + half * 256 + l * 4);
        }
    };
    auto writeB = [&](char* buf, int p, float4* L) {
#pragma unroll
        for (int i = 0; i < 8; ++i) {
            int row  = w * 16 + p * 4 + (i >> 1);
            int half = i & 1;
            int g16  = half * 32 + (l >> 1);
            int byte = row * 1024 + ((g16 * 16) ^ ((row & 7) << 4)) + (l & 1) * 8;
            u16 h[4];
            h[0] = f2bf(L[i].x); h[1] = f2bf(L[i].y);
            h[2] = f2bf(L[i].z); h[3] = f2bf(L[i].w);
            *(uint2*)(buf + byte) = *(uint2*)h;
        }
    };

    // ---- prologue: stage tile0 into buf0 ----
    issueB(tile0, 0, LA);
    issueB(tile0, 1, LB);
    writeB(smem + BUF0_OFF, 0, LA);
    issueB(tile0, 2, LA);
    writeB(smem + BUF0_OFF, 1, LB);
    issueB(tile0, 3, LB);
    writeB(smem + BUF0_OFF, 2, LA);
    writeB(smem + BUF0_OFF, 3, LB);
    barrier_lds();

    bf16x8 bA[8], bB[8];
#pragma unroll
    for (int n = 0; n < 8; ++n)
        bA[n] = *(const bf16x8*)(Wbb + bOffBase + n * 1024);

    int cur = 0;
#pragma unroll 1
    for (int t = 0; t < TILES; ++t) {
        char* bufC = smem + (cur ? BUF1_OFF : BUF0_OFF);
        char* bufN = smem + (cur ? BUF0_OFF : BUF1_OFF);
        const bool more  = (t + 1 < TILES);
        const int  tNext = tile0 + t + 1;
        const int  nodeBase = (tile0 + t) * BM;

        f32x4 acc[4][8];
#pragma unroll
        for (int m = 0; m < 4; ++m)
#pragma unroll
            for (int n = 0; n < 8; ++n) acc[m][n] = (f32x4){0.f, 0.f, 0.f, 0.f};

        // ---- K-loop: 8 kk2 (pairs of 32-k steps); next-tile staging interleaved ----
#pragma unroll 1
        for (int kk2 = 0; kk2 < 8; ++kk2) {
            if (more && kk2 == 0) issueB(tNext, 0, LA);
            if (more && kk2 == 2) issueB(tNext, 1, LB);
            if (more && kk2 == 5) writeB(bufN, 0, LA);
            if (more && kk2 == 7) writeB(bufN, 1, LB);
            {   // half A: compute kk=2*kk2 with bA; prefetch bB
                const char* Wn = Wbb + ((size_t)(2 * kk2 + 1) << 15);
#pragma unroll
                for (int n = 0; n < 8; ++n)
                    bB[n] = *(const bf16x8*)(Wn + bOffBase + n * 1024);
                bf16x8 a[4];
                const int kbyte = (2 * kk2) * 64 + lhi * 16;
#pragma unroll
                for (int m = 0; m < 4; ++m) {
                    int row = m * 16 + l15;
                    a[m] = *(const bf16x8*)(bufC + row * 1024 + (kbyte ^ ((row & 7) << 4)));
                }
#pragma unroll
                for (int m = 0; m < 4; ++m)
#pragma unroll
                    for (int n = 0; n < 8; ++n)
                        acc[m][n] = __builtin_amdgcn_mfma_f32_16x16x32_bf16(a[m], bA[n], acc[m][n], 0, 0, 0);
            }
            {   // half B: compute kk=2*kk2+1 with bB; prefetch bA
                if (kk2 < 7) {
                    const char* Wn = Wbb + ((size_t)(2 * kk2 + 2) << 15);
#pragma unroll
                    for (int n = 0; n < 8; ++n)
                        bA[n] = *(const bf16x8*)(Wn + bOffBase + n * 1024);
                }
                bf16x8 a[4];
                const int kbyte = (2 * kk2 + 1) * 64 + lhi * 16;
#pragma unroll
                for (int m = 0; m < 4; ++m) {
                    int row = m * 16 + l15;
                    a[m] = *(const bf16x8*)(bufC + row * 1024 + (kbyte ^ ((row & 7) << 4)));
                }
#pragma unroll
                for (int m = 0; m < 4; ++m)
#pragma unroll
                    for (int n = 0; n < 8; ++n)
                        acc[m][n] = __builtin_amdgcn_mfma_f32_16x16x32_bf16(a[m], bB[n], acc[m][n], 0, 0, 0);
            }
        }

        // ---- next-tile staging continues under the epilogue ----
        if (more) issueB(tNext, 2, LA);
        if (more) {   // preload bA for next tile's first slab
#pragma unroll
            for (int n = 0; n < 8; ++n)
                bA[n] = *(const bf16x8*)(Wbb + bOffBase + n * 1024);
        }

        // ---- epilogue: beta-partial over this wave's 128 cols ----
        float Vv[8];
#pragma unroll
        for (int n = 0; n < 8; ++n)
            Vv[n] = V[w * 128 + n * 16 + l15];

        float bsum[4][4];
#pragma unroll
        for (int m = 0; m < 4; ++m)
#pragma unroll
            for (int r = 0; r < 4; ++r) {
                float s = 0.f;
#pragma unroll
                for (int n = 0; n < 8; ++n)
                    s += Vv[n] * fast_tanh(acc[m][n][r]);
                bsum[m][r] = s;
            }
#pragma unroll
        for (int off = 1; off <= 8; off <<= 1)
#pragma unroll
            for (int m = 0; m < 4; ++m)
#pragma unroll
                for (int r = 0; r < 4; ++r)
                    bsum[m][r] += __shfl_xor(bsum[m][r], off, 64);

        if (more) writeB(bufN, 2, LA);

        float* betaP = (float*)(smem + BETA_OFF);   // [4 col-groups][64 rows]
        if (l15 == 0) {
#pragma unroll
            for (int m = 0; m < 4; ++m)
#pragma unroll
                for (int r = 0; r < 4; ++r)
                    betaP[w * BM + m * 16 + lhi * 4 + r] = bsum[m][r];
        }
        barrier_lds();

        if (more) issueB(tNext, 3, LB);

        // ---- eb = exp(beta); S[g] += eb (wave 0; rows sorted) ----
        float* ebs  = (float*)(smem + EBS_OFF);
        int*   sidx = (int*)(smem + SIDX_OFF);
        if (tid < BM) {
            float beta = betaP[tid] + betaP[BM + tid] + betaP[2 * BM + tid] + betaP[3 * BM + tid];
            float eb = expf(beta);
            ebs[tid] = eb;
            int g = BI[nodeBase + tid];
            sidx[tid] = g;
            int g0 = __shfl(g, 0, 64);
            if (__all(g == g0)) {
                float s = eb;
#pragma unroll
                for (int off = 1; off <= 32; off <<= 1)
                    s += __shfl_xor(s, off, 64);
                if (l == 0) atomicAdd(&S[g], s);
            } else {
                atomicAdd(&S[g], eb);
            }
        }
        barrier_lds();

        // ---- weighted segment sum: wave w rows [16w,16w+16); lane l cols [8l,8l+8).
        // Flush transposes through per-wave LDS scratch -> lane-contiguous atomics.
        {
            float* scr = (float*)(smem + SCR_OFF) + w * 512;
            const int rbase = w * 16;
            float a8[8];
#pragma unroll
            for (int j = 0; j < 8; ++j) a8[j] = 0.f;
            int gcur = sidx[rbase];

#pragma unroll 1
            for (int rr = 0; rr < 16; ++rr) {
                int r = rbase + rr;
                int g = sidx[r];                     // wave-uniform
                if (g != gcur) {
                    *(float4*)(scr + l * 8)     = make_float4(a8[0], a8[1], a8[2], a8[3]);
                    *(float4*)(scr + l * 8 + 4) = make_float4(a8[4], a8[5], a8[6], a8[7]);
                    asm volatile("s_waitcnt lgkmcnt(0)" ::: "memory");
#pragma unroll
                    for (int j = 0; j < 8; ++j)
                        atomicAdd(&out[(size_t)gcur * 512 + j * 64 + l], scr[j * 64 + l]);
#pragma unroll
                    for (int j = 0; j < 8; ++j) a8[j] = 0.f;
                    gcur = g;
                }
                float wgt = ebs[r];
                bf16x8 v = *(const bf16x8*)(bufC + r * 1024 + ((l * 16) ^ ((r & 7) << 4)));
#pragma unroll
                for (int j = 0; j < 8; ++j)
                    a8[j] += wgt * bf2f((u16)v[j]);
            }
            *(float4*)(scr + l * 8)     = make_float4(a8[0], a8[1], a8[2], a8[3]);
            *(float4*)(scr + l * 8 + 4) = make_float4(a8[4], a8[5], a8[6], a8[7]);
            asm volatile("s_waitcnt lgkmcnt(0)" ::: "memory");
#pragma unroll
            for (int j = 0; j < 8; ++j)
                atomicAdd(&out[(size_t)gcur * 512 + j * 64 + l], scr[j * 64 + l]);
        }

        if (more) writeB(bufN, 3, LB);
        barrier_lds();
        cur ^= 1;
    }
}

__global__ __launch_bounds__(256)
void finalize_kernel(float* __restrict__ out, const float* __restrict__ S) {
    int idx = blockIdx.x * 256 + threadIdx.x;
    float s = S[idx >> 9];
    float v = out[idx];
    out[idx] = (s != 0.f) ? v * __builtin_amdgcn_rcpf(s) : 0.f;
}

extern "C" void kernel_launch(void* const* d_in, const int* in_sizes, int n_in,
                              void* d_out, int out_size, void* d_ws, size_t ws_size,
                              hipStream_t stream) {
    const float* E  = (const float*)d_in[0];
    const int*   BI = (const int*)d_in[1];
    const float* W  = (const float*)d_in[2];
    const float* V  = (const float*)d_in[3];
    float* out = (float*)d_out;
    char*  ws  = (char*)d_ws;
    const int Ntot = in_sizes[0] / D_DIM;

    float* S  = (float*)(ws + WS_S);
    u16*   Wb = (u16*)(ws + WS_WB);

    hipMemsetAsync(S, 0, G_SEG * 4, stream);
    hipMemsetAsync(out, 0, (size_t)out_size * 4, stream);
    hipFuncSetAttribute((const void*)fused,
                        hipFuncAttributeMaxDynamicSharedMemorySize, LDS_TOTAL);

    cvt_w<<<128, 256, 0, stream>>>(W, Wb);
    fused<<<Ntot / (BM * TILES), 256, LDS_TOTAL, stream>>>(E, BI, Wb, V, out, S);
    finalize_kernel<<<out_size / 256, 256, 0, stream>>>(out, S);
}